// Round 5
// baseline (136.048 us; speedup 1.0000x reference)
//
#include <hip/hip_runtime.h>
#include <math.h>

typedef _Float16 f16;
typedef __attribute__((ext_vector_type(2))) _Float16 f16x2;
typedef __attribute__((ext_vector_type(4))) _Float16 f16x4;
typedef __attribute__((ext_vector_type(8))) _Float16 f16x8;
typedef __attribute__((ext_vector_type(4))) float f32x4;

#define NBATCH 8
#define WSA_ELE 36864      // 32*1152 (w_off padded to 32 rows, k-major, frag-swizzled)
#define WSB_ELE 147456     // 128*1152 (w_def, k-major, frag-swizzled)
#define PREP_BLOCKS 720    // (WSA_ELE + WSB_ELE) / 256
// workspace byte offsets
#define OFF_WSB  73728
#define OFF_XT   368640
#define OFF_OFFM 8757248

__device__ __forceinline__ void gload_lds16(const f16* gsrc, f16* ldst) {
  // per-lane global src; wave-uniform LDS base (HW adds lane*16)
  __builtin_amdgcn_global_load_lds(
      (const __attribute__((address_space(1))) unsigned int*)gsrc,
      (__attribute__((address_space(3))) unsigned int*)ldst, 16, 0, 0);
}

// ---------------- prep (fused): weights->fp16 frag-swizzled  +  x NCHW->NHWC fp16 ----------------
// swizzled element e = ((ch*NFRAG + mt)*64 + lane)*8 + j holds
// W[row = mt*16 + (lane&15)][kidx = ch*32 + (lane>>4)*8 + j], kidx = k*128 + cc.
__global__ __launch_bounds__(256) void prep_kernel(const float* __restrict__ x,
                                                   const float* __restrict__ w_off,
                                                   const float* __restrict__ w_def,
                                                   f16* __restrict__ wsA,
                                                   f16* __restrict__ wsB,
                                                   f16* __restrict__ xt) {
  __shared__ f16 s_t[128 * 66];
  const int bid = blockIdx.x;
  const int t = threadIdx.x;
  if (bid < PREP_BLOCKS) {
    int i = bid * 256 + t;
    if (i < WSA_ELE) {
      int j = i & 7, lane = (i >> 3) & 63, fm = i >> 9;
      int ch = fm >> 1, mt = fm & 1;
      int row = mt * 16 + (lane & 15);
      int kidx = ch * 32 + (lane >> 4) * 8 + j;
      int k = kidx >> 7, cc = kidx & 127;
      float v = (row < 27) ? w_off[row * 1152 + cc * 9 + k] : 0.0f;
      wsA[i] = (f16)v;
    } else {
      int e = i - WSA_ELE;
      int j = e & 7, lane = (e >> 3) & 63, fm = e >> 9;
      int ch = fm >> 3, mt = fm & 7;
      int row = mt * 16 + (lane & 15);
      int kidx = ch * 32 + (lane >> 4) * 8 + j;
      int k = kidx >> 7, cc = kidx & 127;
      wsB[e] = (f16)w_def[row * 1152 + cc * 9 + k];
    }
  } else {
    const int bb = bid - PREP_BLOCKS;
    const int b = bb >> 6;
    const int pos0 = (bb & 63) << 6;
    const float* xb = x + ((size_t)b << 19);
    for (int i = t; i < 8192; i += 256) {
      int c = i >> 6, p = i & 63;
      s_t[c * 66 + p] = (f16)xb[c * 4096 + pos0 + p];
    }
    __syncthreads();
    f16* xtb = xt + ((size_t)b << 19);
    for (int i = t; i < 4096; i += 256) {
      int p = i >> 6, c2 = (i & 63) * 2;
      unsigned v0 = *(const unsigned short*)&s_t[c2 * 66 + p];
      unsigned v1 = *(const unsigned short*)&s_t[(c2 + 1) * 66 + p];
      *(unsigned*)&xtb[(size_t)(pos0 + p) * 128 + c2] = v0 | (v1 << 16);
    }
  }
}

// ---------------- offset conv: barrier-free im2col MFMA (M=32, k-major K) ----------------
__global__ __launch_bounds__(256) void offset_conv_kernel(const f16* __restrict__ xt,
                                                          const f16* __restrict__ wsA,
                                                          const float* __restrict__ b_off,
                                                          float* __restrict__ offm) {
  const int t = threadIdx.x;
  const int b = blockIdx.x >> 6, ho = blockIdx.x & 63;
  const int lane = t & 63, wid = t >> 6;
  const int q = lane >> 4, li = lane & 15;
  const int px = (wid << 4) + li;
  const char* xtb = (const char*)xt + ((size_t)b << 20);

  f32x4 acc0 = {0.f, 0.f, 0.f, 0.f}, acc1 = {0.f, 0.f, 0.f, 0.f};

  for (int k = 0; k < 9; ++k) {
    const int ky = k / 3, kx = k - ky * 3;
    const int y = ho + ky - 1;
    const int xx = px + kx - 1;
    const bool valid = ((unsigned)y < 64u) && ((unsigned)xx < 64u);
    const int pos = min(max(y, 0), 63) * 64 + min(max(xx, 0), 63);
    const int voff = pos * 256 + q * 16;
    #pragma unroll
    for (int c4 = 0; c4 < 4; ++c4) {
      union { uint4 u; f16x8 v; } bu;
      bu.u = *(const uint4*)(xtb + voff + c4 * 64);
      if (!valid) { bu.u.x = 0u; bu.u.y = 0u; bu.u.z = 0u; bu.u.w = 0u; }
      const int ch = k * 4 + c4;
      f16x8 a0 = *(const f16x8*)&wsA[(ch * 2    ) * 512 + lane * 8];
      f16x8 a1 = *(const f16x8*)&wsA[(ch * 2 + 1) * 512 + lane * 8];
      acc0 = __builtin_amdgcn_mfma_f32_16x16x32_f16(a0, bu.v, acc0, 0, 0, 0);
      acc1 = __builtin_amdgcn_mfma_f32_16x16x32_f16(a1, bu.v, acc1, 0, 0, 0);
    }
  }

  float* om = offm + (size_t)b * 27 * 4096 + ho * 64 + px;
  #pragma unroll
  for (int mt = 0; mt < 2; ++mt) {
    f32x4 a = mt ? acc1 : acc0;
    #pragma unroll
    for (int r = 0; r < 4; ++r) {
      int oc = mt * 16 + q * 4 + r;
      if (oc < 27) {
        float v = a[r] + b_off[oc];
        if (oc >= 18) v = 1.0f / (1.0f + __expf(-v));
        om[oc * 4096] = v;
      }
    }
  }
}

// ---------------- DCNv2: reg-sampled B (packed fp16 bilinear) + single-buffer LDS A ----------------
__global__ __launch_bounds__(256, 5) void dcn_kernel(const f16* __restrict__ xt,
                                                     const f16* __restrict__ wsB,
                                                     const float* __restrict__ offm,
                                                     const float* __restrict__ b_def,
                                                     float* __restrict__ out) {
  __shared__ ushort4 s_pos[576];               // 4608 B: per-(k,px) corner position idx
  __shared__ f16x4   s_wth[576];               // 4608 B: per-(k,px) modulated weights (f16)
  __shared__ __align__(16) f16 s_a[8192];      // 16 KB: A chunk (2 c4-steps, K=64)
  const int t = threadIdx.x;
  const int b = blockIdx.x >> 6, ho = blockIdx.x & 63;
  const int lane = t & 63, wid = t >> 6;
  const int q = lane >> 4, li = lane & 15;
  const int px0 = wid << 4;
  const char* xtb = (const char*)xt + ((size_t)b << 20);

  // bilinear table: ci-invariant corner positions + mask-premultiplied weights
  const float* ob = offm + (size_t)b * 27 * 4096 + ho * 64;
  for (int f = t; f < 576; f += 256) {
    int k = f >> 6, p = f & 63;
    int ky = k / 3, kx = k - ky * 3;
    float oy = ob[(2 * k    ) * 4096 + p];
    float ox = ob[(2 * k + 1) * 4096 + p];
    float m  = ob[(18 + k   ) * 4096 + p];
    float py  = oy + (float)(ho + ky - 1);
    float pxf = ox + (float)(p + kx - 1);
    float y0f = floorf(py), x0f = floorf(pxf);
    float wy = py - y0f, wx = pxf - x0f;
    int y0 = (int)y0f, x0 = (int)x0f;
    int y1 = y0 + 1, x1 = x0 + 1;
    bool y0v = (unsigned)y0 < 64u, y1v = (unsigned)y1 < 64u;
    bool x0v = (unsigned)x0 < 64u, x1v = (unsigned)x1 < 64u;
    int y0c = min(max(y0, 0), 63), y1c = min(max(y1, 0), 63);
    int x0c = min(max(x0, 0), 63), x1c = min(max(x1, 0), 63);
    ushort4 p4;
    p4.x = (unsigned short)(y0c * 64 + x0c);
    p4.y = (unsigned short)(y0c * 64 + x1c);
    p4.z = (unsigned short)(y1c * 64 + x0c);
    p4.w = (unsigned short)(y1c * 64 + x1c);
    f16x4 wh;
    wh[0] = (f16)((y0v && x0v) ? (1.f - wy) * (1.f - wx) * m : 0.f);
    wh[1] = (f16)((y0v && x1v) ? (1.f - wy) * wx         * m : 0.f);
    wh[2] = (f16)((y1v && x0v) ? wy         * (1.f - wx) * m : 0.f);
    wh[3] = (f16)((y1v && x1v) ? wy         * wx         * m : 0.f);
    s_pos[f] = p4;
    s_wth[f] = wh;
  }

  f32x4 acc[8];
  #pragma unroll
  for (int mt = 0; mt < 8; ++mt) acc[mt] = (f32x4){0.f, 0.f, 0.f, 0.f};

  for (int c4g = 0; c4g < 36; ++c4g) {
    const int k = c4g >> 2, c4 = c4g & 3, sub = c4g & 1;
    if (sub == 0) {
      __syncthreads();   // prior chunk's A reads done (also: table ready on first iter)
      const f16* src = wsB + c4g * 4096 + wid * 2048 + lane * 8;
      f16* dst = &s_a[wid * 2048];
      gload_lds16(src,        dst);
      gload_lds16(src +  512, dst +  512);
      gload_lds16(src + 1024, dst + 1024);
      gload_lds16(src + 1536, dst + 1536);
      __syncthreads();   // vmcnt(0) drain before barrier completes staging
    }
    const int e = k * 64 + px0 + li;
    const ushort4 p4 = s_pos[e];
    const f16x4   w4 = s_wth[e];
    const unsigned cb = (unsigned)(c4 * 64 + q * 16);
    union { uint4 u; f16x2 h[4]; } d0, d1, d2, d3;
    d0.u = *(const uint4*)(xtb + (((unsigned)p4.x << 8) + cb));
    d1.u = *(const uint4*)(xtb + (((unsigned)p4.y << 8) + cb));
    d2.u = *(const uint4*)(xtb + (((unsigned)p4.z << 8) + cb));
    d3.u = *(const uint4*)(xtb + (((unsigned)p4.w << 8) + cb));
    const f16x2 wp0 = {w4[0], w4[0]}, wp1 = {w4[1], w4[1]};
    const f16x2 wp2 = {w4[2], w4[2]}, wp3 = {w4[3], w4[3]};
    union { f16x2 h[4]; f16x8 v; } bf;
    #pragma unroll
    for (int i = 0; i < 4; ++i) {
      f16x2 s = d0.h[i] * wp0;
      s = s + d1.h[i] * wp1;
      s = s + d2.h[i] * wp2;
      s = s + d3.h[i] * wp3;
      bf.h[i] = s;
    }
    const f16* ab = &s_a[sub * 4096];
    #pragma unroll
    for (int mt = 0; mt < 8; ++mt) {
      f16x8 a = *(const f16x8*)&ab[(mt * 64 + lane) * 8];
      acc[mt] = __builtin_amdgcn_mfma_f32_16x16x32_f16(a, bf.v, acc[mt], 0, 0, 0);
    }
  }

  float* o = out + (size_t)b * 128 * 4096 + ho * 64 + px0 + li;
  #pragma unroll
  for (int mt = 0; mt < 8; ++mt) {
    #pragma unroll
    for (int r = 0; r < 4; ++r) {
      int oc = mt * 16 + q * 4 + r;
      o[oc * 4096] = acc[mt][r] + b_def[oc];
    }
  }
}

extern "C" void kernel_launch(void* const* d_in, const int* in_sizes, int n_in,
                              void* d_out, int out_size, void* d_ws, size_t ws_size,
                              hipStream_t stream) {
  const float* x     = (const float*)d_in[0];
  const float* w_off = (const float*)d_in[1];
  const float* b_off = (const float*)d_in[2];
  const float* w_def = (const float*)d_in[3];
  const float* b_def = (const float*)d_in[4];
  float* out = (float*)d_out;

  f16*   wsA  = (f16*)d_ws;
  f16*   wsB  = (f16*)((char*)d_ws + OFF_WSB);
  f16*   xt   = (f16*)((char*)d_ws + OFF_XT);
  float* offm = (float*)((char*)d_ws + OFF_OFFM);

  prep_kernel<<<dim3(PREP_BLOCKS + NBATCH * 64), dim3(256), 0, stream>>>(x, w_off, w_def, wsA, wsB, xt);
  offset_conv_kernel<<<dim3(NBATCH * 64), dim3(256), 0, stream>>>(xt, wsA, b_off, offm);
  dcn_kernel<<<dim3(NBATCH * 64), dim3(256), 0, stream>>>(xt, wsB, offm, b_def, out);
}